// Round 1
// baseline (488.994 us; speedup 1.0000x reference)
//
#include <hip/hip_runtime.h>
#include <stdint.h>

#define NB   16
#define CIN  512
#define COUT 512
#define HH   64
#define WW   64
#define NCOND 512
#define TAPS 9
#define EPSD 1e-8f

typedef short bf16x8 __attribute__((ext_vector_type(8)));
typedef float f32x4 __attribute__((ext_vector_type(4)));

static __device__ __forceinline__ short f2bf(float f) {
  union { float f; uint32_t u; } c;
  c.f = f;
  uint32_t u = c.u;
  uint32_t r = (u + 0x7FFFu + ((u >> 16) & 1u)) >> 16;
  return (short)(uint16_t)r;
}

// ---------------- k1: gamma[b,i] = b_gamma[i] + sum_c y[b,c]*w_gamma[i,c] ----
__global__ __launch_bounds__(512) void k_gamma(const float* __restrict__ y,
                                               const float* __restrict__ w_gamma,
                                               const float* __restrict__ b_gamma,
                                               float* __restrict__ gamma) {
  __shared__ float ys[NCOND];
  const int b = blockIdx.x;
  const int i = threadIdx.x;
  ys[i] = y[b * NCOND + i];
  __syncthreads();
  const float4* wg = reinterpret_cast<const float4*>(w_gamma + (size_t)i * NCOND);
  float acc = b_gamma[i];
  for (int c4 = 0; c4 < NCOND / 4; ++c4) {
    float4 w4 = wg[c4];
    acc += w4.x * ys[c4 * 4 + 0] + w4.y * ys[c4 * 4 + 1] +
           w4.z * ys[c4 * 4 + 2] + w4.w * ys[c4 * 4 + 3];
  }
  gamma[b * CIN + i] = acc;
}

// ---------------- k2: s2[o,i] = sum_tap w^2 ; Wr[o][tap][i] = bf16(w) --------
__global__ __launch_bounds__(256) void k_prep(const float* __restrict__ w_conv,
                                              float* __restrict__ s2,
                                              short* __restrict__ Wr) {
  __shared__ float ws_s[CIN * TAPS];
  const int o = blockIdx.x;
  const int t = threadIdx.x;
  const float* wsrc = w_conv + (size_t)o * CIN * TAPS;
  for (int idx = t; idx < CIN * TAPS; idx += 256) ws_s[idx] = wsrc[idx];
  __syncthreads();
  for (int i = t; i < CIN; i += 256) {
    float s = 0.f;
#pragma unroll
    for (int tap = 0; tap < TAPS; ++tap) {
      float v = ws_s[i * TAPS + tap];
      s += v * v;
    }
    s2[(size_t)o * CIN + i] = s;
  }
  for (int idx = t; idx < CIN * TAPS; idx += 256) {
    int i = idx & (CIN - 1);
    int tap = idx >> 9;
    Wr[((size_t)o * TAPS + tap) * CIN + i] = f2bf(ws_s[i * TAPS + tap]);
  }
}

// ---------------- k3: d[b,o] = rsqrt(sum_i gamma^2 * s2 + eps) ---------------
__global__ __launch_bounds__(512) void k_d(const float* __restrict__ gamma,
                                           const float* __restrict__ s2,
                                           float* __restrict__ dscale) {
  __shared__ float g2[CIN];
  const int b = blockIdx.x;
  const int o = threadIdx.x;
  float g = gamma[b * CIN + o];
  g2[o] = g * g;
  __syncthreads();
  const float4* s4 = reinterpret_cast<const float4*>(s2 + (size_t)o * CIN);
  float acc = 0.f;
  for (int i4 = 0; i4 < CIN / 4; ++i4) {
    float4 v = s4[i4];
    acc += v.x * g2[i4 * 4 + 0] + v.y * g2[i4 * 4 + 1] +
           v.z * g2[i4 * 4 + 2] + v.w * g2[i4 * 4 + 3];
  }
  dscale[b * COUT + o] = rsqrtf(acc + EPSD);
}

// ---------------- k4: conv as implicit GEMM, bf16 MFMA -----------------------
// grid (32 spatial row-pairs, 4 cout tiles, 16 batch), 256 threads (4 waves 2x2)
// out tile: 128 cout x 128 px (2 rows x 64 cols). K = 9 taps x 512 cin,
// chunked 64-cin at a time, taps inner with per-tap A reload.
__global__ __launch_bounds__(256) void k_conv(const float* __restrict__ x,
                                              const short* __restrict__ Wr,
                                              const float* __restrict__ gamma,
                                              const float* __restrict__ dscale,
                                              float* __restrict__ out) {
  __shared__ short As[128 * 64];   // [o][k] bf16, 128B rows, XOR-swizzled content
  __shared__ short Xs[4 * 64 * 64]; // [row4][c][i] bf16, 128B rows, XOR-swizzled
  __shared__ float gam_s[CIN];
  __shared__ float d_s[128];

  const int sp = blockIdx.x;  // row-pair: output rows 2*sp, 2*sp+1
  const int ot = blockIdx.y;  // cout tile * 128
  const int b  = blockIdx.z;
  const int t  = threadIdx.x;
  const int lane = t & 63;
  const int wv = t >> 6;
  const int wr = wv >> 1;  // cout half
  const int wc = wv & 1;   // pixel half

  gam_s[t] = gamma[b * CIN + t];
  gam_s[t + 256] = gamma[b * CIN + t + 256];
  if (t < 128) d_s[t] = dscale[b * COUT + ot * 128 + t];

  f32x4 acc[4][4];
#pragma unroll
  for (int m = 0; m < 4; ++m)
#pragma unroll
    for (int n = 0; n < 4; ++n)
      acc[m][n] = (f32x4){0.f, 0.f, 0.f, 0.f};

  // Xs staging constants: each thread owns one (row, c) slot, loops over cin
  const int srow = t >> 6;  // 0..3 (== wave)
  const int sc = t & 63;
  const int ysrc = sp * 2 + srow - 1;
  const bool rv = (ysrc >= 0) && (ysrc < HH);
  const int ycl = rv ? ysrc : 0;
  const float* xrow = x + (((size_t)b * CIN) * HH + ycl) * WW + sc;
  short* xs_base = &Xs[(srow * 64 + sc) * 64];
  const int xs_sw = (sc & 7) << 4;

  for (int chunk = 0; chunk < CIN / 64; ++chunk) {
    const int i0 = chunk * 64;
    __syncthreads();  // Xs free (prev chunk's MFMAs done)
    {
      const float* xp = xrow + (size_t)i0 * (HH * WW);
#pragma unroll
      for (int i8 = 0; i8 < 8; ++i8) {
        short tmp[8];
#pragma unroll
        for (int j = 0; j < 8; ++j) {
          int i = i8 * 8 + j;
          float v = rv ? xp[i * (HH * WW)] : 0.0f;
          tmp[j] = f2bf(v * gam_s[i0 + i]);
        }
        char* dst = (char*)xs_base + ((i8 * 16) ^ xs_sw);
        *reinterpret_cast<bf16x8*>(dst) = *reinterpret_cast<const bf16x8*>(tmp);
      }
    }
    for (int tap = 0; tap < TAPS; ++tap) {
      __syncthreads();  // As free; (tap==0) Xs ready
      // stage As: linear dest, pre-swizzled source (global_load_lds-compatible)
#pragma unroll
      for (int j = 0; j < 4; ++j) {
        int s = t + 256 * j;
        int row = s >> 3, sl = s & 7;
        int kbyte = (sl * 16) ^ ((row & 7) << 4);
        const short* src = Wr + ((size_t)(ot * 128 + row) * TAPS + tap) * CIN +
                           i0 + (kbyte >> 1);
        *reinterpret_cast<bf16x8*>((char*)As + row * 128 + sl * 16) =
            *reinterpret_cast<const bf16x8*>(src);
      }
      __syncthreads();

      const int dy = tap / 3 - 1, dx = tap % 3 - 1;
      bf16x8 afr[2][4], bfr[2][4];
#pragma unroll
      for (int kk = 0; kk < 2; ++kk) {
        const int kb = kk * 64 + (lane >> 4) * 16;  // byte offset of k in row
#pragma unroll
        for (int m = 0; m < 4; ++m) {
          int row = wr * 64 + m * 16 + (lane & 15);
          afr[kk][m] = *reinterpret_cast<const bf16x8*>(
              (const char*)As + row * 128 + (kb ^ ((row & 7) << 4)));
        }
#pragma unroll
        for (int n = 0; n < 4; ++n) {
          int p = wc * 64 + n * 16 + (lane & 15);
          int r = p >> 6, c = p & 63;
          int cc = c + dx;
          bool val = (cc >= 0) && (cc < WW);
          int ccl = val ? cc : 0;
          int rr = r + dy + 1;
          bf16x8 f = *reinterpret_cast<const bf16x8*>(
              (const char*)Xs + (rr * 64 + ccl) * 128 + (kb ^ ((ccl & 7) << 4)));
          if (!val) f = (bf16x8){0, 0, 0, 0, 0, 0, 0, 0};
          bfr[kk][n] = f;
        }
      }
#pragma unroll
      for (int m = 0; m < 4; ++m)
#pragma unroll
        for (int n = 0; n < 4; ++n)
#pragma unroll
          for (int kk = 0; kk < 2; ++kk)
            acc[m][n] = __builtin_amdgcn_mfma_f32_16x16x32_bf16(
                afr[kk][m], bfr[kk][n], acc[m][n], 0, 0, 0);
    }
  }

  // epilogue: out = d[b,o] * acc
#pragma unroll
  for (int m = 0; m < 4; ++m) {
#pragma unroll
    for (int n = 0; n < 4; ++n) {
#pragma unroll
      for (int j = 0; j < 4; ++j) {
        int o_l = wr * 64 + m * 16 + (lane >> 4) * 4 + j;
        int o = ot * 128 + o_l;
        int p = wc * 64 + n * 16 + (lane & 15);
        int yy = sp * 2 + (p >> 6);
        int cx = p & 63;
        out[(((size_t)b * COUT + o) * HH + yy) * WW + cx] = d_s[o_l] * acc[m][n][j];
      }
    }
  }
}

extern "C" void kernel_launch(void* const* d_in, const int* in_sizes, int n_in,
                              void* d_out, int out_size, void* d_ws, size_t ws_size,
                              hipStream_t stream) {
  const float* x = (const float*)d_in[0];
  const float* y = (const float*)d_in[1];
  const float* w_conv = (const float*)d_in[2];
  const float* w_gamma = (const float*)d_in[3];
  const float* b_gamma = (const float*)d_in[4];
  float* out = (float*)d_out;

  char* ws = (char*)d_ws;
  short* Wr = (short*)ws;                                  // 512*9*512*2 = 4718592 B
  float* gamma = (float*)(ws + 4718592);                   // 32768 B
  float* dsc = (float*)(ws + 4718592 + 32768);             // 32768 B
  float* s2 = (float*)(ws + 4718592 + 65536);              // 1 MiB

  hipLaunchKernelGGL(k_gamma, dim3(NB), dim3(512), 0, stream, y, w_gamma, b_gamma, gamma);
  hipLaunchKernelGGL(k_prep, dim3(COUT), dim3(256), 0, stream, w_conv, s2, Wr);
  hipLaunchKernelGGL(k_d, dim3(NB), dim3(512), 0, stream, gamma, s2, dsc);
  hipLaunchKernelGGL(k_conv, dim3(32, 4, NB), dim3(256), 0, stream, x, Wr, gamma, dsc, out);
}

// Round 2
// 415.291 us; speedup vs baseline: 1.1775x; 1.1775x over previous
//
#include <hip/hip_runtime.h>
#include <stdint.h>

#define NB   16
#define CIN  512
#define COUT 512
#define HH   64
#define WW   64
#define NCOND 512
#define TAPS 9
#define EPSD 1e-8f

typedef short bf16x8 __attribute__((ext_vector_type(8)));
typedef float f32x4 __attribute__((ext_vector_type(4)));

static __device__ __forceinline__ short f2bf(float f) {
  union { float f; uint32_t u; } c;
  c.f = f;
  uint32_t u = c.u;
  uint32_t r = (u + 0x7FFFu + ((u >> 16) & 1u)) >> 16;
  return (short)(uint16_t)r;
}

static __device__ __forceinline__ void gl_lds16(const void* g, void* l) {
  __builtin_amdgcn_global_load_lds(
      (const __attribute__((address_space(1))) void*)g,
      (__attribute__((address_space(3))) void*)l, 16, 0, 0);
}

// ---------------- k1: gamma[b,i] = b_gamma[i] + sum_c y[b,c]*w_gamma[i,c] ----
// also zeroes the 576-short zero page used for halo-row gload_lds sources
__global__ __launch_bounds__(512) void k_gamma(const float* __restrict__ y,
                                               const float* __restrict__ w_gamma,
                                               const float* __restrict__ b_gamma,
                                               float* __restrict__ gamma,
                                               float* __restrict__ zbuf) {
  __shared__ float ys[NCOND];
  const int b = blockIdx.x;
  const int i = threadIdx.x;
  if (zbuf && b == 0 && i < 288) zbuf[i] = 0.f;  // 1152B of zeros
  ys[i] = y[b * NCOND + i];
  __syncthreads();
  const float4* wg = reinterpret_cast<const float4*>(w_gamma + (size_t)i * NCOND);
  float acc = b_gamma[i];
  for (int c4 = 0; c4 < NCOND / 4; ++c4) {
    float4 w4 = wg[c4];
    acc += w4.x * ys[c4 * 4 + 0] + w4.y * ys[c4 * 4 + 1] +
           w4.z * ys[c4 * 4 + 2] + w4.w * ys[c4 * 4 + 3];
  }
  gamma[b * CIN + i] = acc;
}

// ---------------- k2: s2[o,i] = sum_tap w^2 ; Wr[o][tap][i] = bf16(w) --------
__global__ __launch_bounds__(256) void k_prep(const float* __restrict__ w_conv,
                                              float* __restrict__ s2,
                                              short* __restrict__ Wr) {
  __shared__ float ws_s[CIN * TAPS];
  const int o = blockIdx.x;
  const int t = threadIdx.x;
  const float* wsrc = w_conv + (size_t)o * CIN * TAPS;
  for (int idx = t; idx < CIN * TAPS; idx += 256) ws_s[idx] = wsrc[idx];
  __syncthreads();
  for (int i = t; i < CIN; i += 256) {
    float s = 0.f;
#pragma unroll
    for (int tap = 0; tap < TAPS; ++tap) {
      float v = ws_s[i * TAPS + tap];
      s += v * v;
    }
    s2[(size_t)o * CIN + i] = s;
  }
  for (int idx = t; idx < CIN * TAPS; idx += 256) {
    int i = idx & (CIN - 1);
    int tap = idx >> 9;
    Wr[((size_t)o * TAPS + tap) * CIN + i] = f2bf(ws_s[i * TAPS + tap]);
  }
}

// ---------------- k3: d[b,o] = rsqrt(sum_i gamma^2 * s2 + eps) ---------------
__global__ __launch_bounds__(512) void k_d(const float* __restrict__ gamma,
                                           const float* __restrict__ s2,
                                           float* __restrict__ dscale) {
  __shared__ float g2[CIN];
  const int b = blockIdx.x;
  const int o = threadIdx.x;
  float g = gamma[b * CIN + o];
  g2[o] = g * g;
  __syncthreads();
  const float4* s4 = reinterpret_cast<const float4*>(s2 + (size_t)o * CIN);
  float acc = 0.f;
  for (int i4 = 0; i4 < CIN / 4; ++i4) {
    float4 v = s4[i4];
    acc += v.x * g2[i4 * 4 + 0] + v.y * g2[i4 * 4 + 1] +
           v.z * g2[i4 * 4 + 2] + v.w * g2[i4 * 4 + 3];
  }
  dscale[b * COUT + o] = rsqrtf(acc + EPSD);
}

// ---------------- k_xmod: xm[b][y][w][c] = bf16(x[b][c][y][w] * gamma[b][c]) -
__global__ __launch_bounds__(256) void k_xmod(const float* __restrict__ x,
                                              const float* __restrict__ gamma,
                                              short* __restrict__ xm) {
  __shared__ float tile[64][67];
  __shared__ float gs[CIN];
  const int y = blockIdx.x, b = blockIdx.y;
  const int t = threadIdx.x;
  gs[t] = gamma[b * CIN + t];
  gs[t + 256] = gamma[b * CIN + t + 256];
  __syncthreads();
  for (int c0 = 0; c0 < CIN; c0 += 64) {
    {
      int w = t & 63;
      int cb = t >> 6;  // 0..3
      const float* xp = x + (((size_t)(b * CIN + c0 + cb)) * HH + y) * WW + w;
#pragma unroll
      for (int p = 0; p < 16; ++p)
        tile[cb + p * 4][w] = xp[(size_t)p * 4 * HH * WW];
    }
    __syncthreads();
    {
      int w = t >> 2, q = t & 3;
      short* dst = xm + (((size_t)b * HH + y) * WW + w) * CIN + c0 + q * 16;
#pragma unroll
      for (int h = 0; h < 2; ++h) {
        short tmp[8];
#pragma unroll
        for (int j = 0; j < 8; ++j) {
          int c = q * 16 + h * 8 + j;
          tmp[j] = f2bf(tile[c][w] * gs[c0 + c]);
        }
        *reinterpret_cast<bf16x8*>(dst + h * 8) = *reinterpret_cast<const bf16x8*>(tmp);
      }
    }
    __syncthreads();
  }
}

// ---------------- k_conv2: pipelined implicit-GEMM conv ---------------------
// 1-D grid 2048 = (ot 4) x (b 16) x (sp 32), XCD-chunked swizzle.
// 256 thr = 4 waves (2x2). Tile 128 cout x 128 px (2 rows). BK=32 cin,
// steps = 16 chunks x 9 taps, both As and Xs double-buffered, gload_lds
// staging with pre-swizzled sources, one vmcnt(0)+barrier per step.
__global__ __launch_bounds__(256) void k_conv2(const short* __restrict__ xm,
                                               const short* __restrict__ Wr,
                                               const short* __restrict__ zbuf,
                                               const float* __restrict__ dscale,
                                               float* __restrict__ out) {
  __shared__ short As[2][128 * 32];   // 2 x 8KB
  __shared__ short Xs[2][256 * 32];   // 2 x 16KB
  __shared__ float d_s[128];

  const int orig = blockIdx.x;
  const int wgid = ((orig & 7) << 8) | (orig >> 3);  // XCD-chunked (2048%8==0)
  const int ot = wgid >> 9;
  const int b = (wgid >> 5) & 15;
  const int sp = wgid & 31;

  const int t = threadIdx.x, lane = t & 63;
  const int wv = t >> 6;
  const int wr = wv >> 1, wc = wv & 1;
  const int l15 = lane & 15;
  const int kb0 = (lane >> 4) << 4;  // 0,16,32,48 byte k-slot

  if (t < 128) d_s[t] = dscale[b * COUT + ot * 128 + t];

  // A staging: 2 issues/thread; slot=(t+256i): row=slot>>2, sl=slot&3
  int a_term[2];
#pragma unroll
  for (int i = 0; i < 2; ++i) {
    int slot = t + 256 * i;
    int row = slot >> 2, sl = slot & 3;
    int off = ((sl * 16) ^ (((row >> 1) & 3) << 4)) >> 1;  // shorts
    a_term[i] = (ot * 128 + row) * TAPS * CIN + off;
  }
  // X staging: 4 issues/thread; slot=(t+256i): prow=slot>>2, sl=slot&3
  const short* x_src[4];
#pragma unroll
  for (int i = 0; i < 4; ++i) {
    int slot = t + 256 * i;
    int prow = slot >> 2, sl = slot & 3;
    int srow = prow >> 6, w = prow & 63;
    int off = ((sl * 16) ^ (((prow >> 1) & 3) << 4)) >> 1;
    int ysrc = sp * 2 + srow - 1;
    bool rv = (ysrc >= 0) && (ysrc < HH);
    x_src[i] = rv ? xm + (((size_t)b * HH + ysrc) * WW + w) * CIN + off
                  : zbuf + off;  // zbuf has 576 zero shorts; +i0 stays in range
  }

  auto stage_a = [&](int abuf, int i0, int tap_) {
    const short* base = Wr + tap_ * CIN + i0;
#pragma unroll
    for (int i = 0; i < 2; ++i)
      gl_lds16(base + a_term[i], (char*)(&As[abuf][0]) + (t + 256 * i) * 16);
  };
  auto stage_x = [&](int xbuf, int i0) {
#pragma unroll
    for (int i = 0; i < 4; ++i)
      gl_lds16(x_src[i] + i0, (char*)(&Xs[xbuf][0]) + (t + 256 * i) * 16);
  };

  f32x4 acc[4][4];
#pragma unroll
  for (int m = 0; m < 4; ++m)
#pragma unroll
    for (int n = 0; n < 4; ++n)
      acc[m][n] = (f32x4){0.f, 0.f, 0.f, 0.f};

  // prologue
  stage_x(0, 0);
  stage_a(0, 0, 0);
  asm volatile("s_waitcnt vmcnt(0)" ::: "memory");
  __syncthreads();

  int chunk = 0, tap = 0;
  for (int s = 0; s < 16 * TAPS; ++s) {
    const int ab = s & 1, xb = chunk & 1;
    // prefetch next step into alternate buffers
    if (s < 16 * TAPS - 1) {
      int ntap = tap + 1, nch = chunk;
      if (ntap == TAPS) {
        ntap = 0;
        nch = chunk + 1;
        stage_x(nch & 1, nch * 32);
      }
      stage_a(ab ^ 1, nch * 32, ntap);
    }
    const int dy = tap / 3 - 1, dx = tap % 3 - 1;

    bf16x8 afr[4], bfr[4];
#pragma unroll
    for (int m = 0; m < 4; ++m) {
      int row = wr * 64 + m * 16 + l15;
      afr[m] = *reinterpret_cast<const bf16x8*>(
          (const char*)&As[ab][0] + row * 64 + (kb0 ^ (((row >> 1) & 3) << 4)));
    }
#pragma unroll
    for (int n = 0; n < 4; ++n) {
      int c = n * 16 + l15;
      int cc = c + dx;
      bool val = (cc >= 0) && (cc < WW);
      int ccl = val ? cc : 0;
      int prow = (wc + dy + 1) * 64 + ccl;
      bf16x8 f = *reinterpret_cast<const bf16x8*>(
          (const char*)&Xs[xb][0] + prow * 64 + (kb0 ^ (((prow >> 1) & 3) << 4)));
      if (!val) f = (bf16x8){0, 0, 0, 0, 0, 0, 0, 0};
      bfr[n] = f;
    }
#pragma unroll
    for (int m = 0; m < 4; ++m)
#pragma unroll
      for (int n = 0; n < 4; ++n)
        acc[m][n] = __builtin_amdgcn_mfma_f32_16x16x32_bf16(afr[m], bfr[n],
                                                            acc[m][n], 0, 0, 0);
    if (++tap == TAPS) { tap = 0; ++chunk; }
    asm volatile("s_waitcnt vmcnt(0)" ::: "memory");
    __syncthreads();
  }

  // epilogue: out = d[b,o] * acc
#pragma unroll
  for (int m = 0; m < 4; ++m) {
#pragma unroll
    for (int n = 0; n < 4; ++n) {
#pragma unroll
      for (int j = 0; j < 4; ++j) {
        int o_l = wr * 64 + m * 16 + (lane >> 4) * 4 + j;
        int o = ot * 128 + o_l;
        int p = wc * 64 + n * 16 + l15;
        int yy = sp * 2 + (p >> 6);
        int cx = p & 63;
        out[(((size_t)b * COUT + o) * HH + yy) * WW + cx] = d_s[o_l] * acc[m][n][j];
      }
    }
  }
}

// ---------------- fallback conv (round-1 kernel) for small ws ----------------
__global__ __launch_bounds__(256) void k_conv_fb(const float* __restrict__ x,
                                                 const short* __restrict__ Wr,
                                                 const float* __restrict__ gamma,
                                                 const float* __restrict__ dscale,
                                                 float* __restrict__ out) {
  __shared__ short As[128 * 64];
  __shared__ short Xs[4 * 64 * 64];
  __shared__ float gam_s[CIN];
  __shared__ float d_s[128];

  const int sp = blockIdx.x;
  const int ot = blockIdx.y;
  const int b  = blockIdx.z;
  const int t  = threadIdx.x;
  const int lane = t & 63;
  const int wv = t >> 6;
  const int wr = wv >> 1;
  const int wc = wv & 1;

  gam_s[t] = gamma[b * CIN + t];
  gam_s[t + 256] = gamma[b * CIN + t + 256];
  if (t < 128) d_s[t] = dscale[b * COUT + ot * 128 + t];

  f32x4 acc[4][4];
#pragma unroll
  for (int m = 0; m < 4; ++m)
#pragma unroll
    for (int n = 0; n < 4; ++n)
      acc[m][n] = (f32x4){0.f, 0.f, 0.f, 0.f};

  const int srow = t >> 6;
  const int sc = t & 63;
  const int ysrc = sp * 2 + srow - 1;
  const bool rv = (ysrc >= 0) && (ysrc < HH);
  const int ycl = rv ? ysrc : 0;
  const float* xrow = x + (((size_t)b * CIN) * HH + ycl) * WW + sc;
  short* xs_base = &Xs[(srow * 64 + sc) * 64];
  const int xs_sw = (sc & 7) << 4;

  for (int chunk = 0; chunk < CIN / 64; ++chunk) {
    const int i0 = chunk * 64;
    __syncthreads();
    {
      const float* xp = xrow + (size_t)i0 * (HH * WW);
#pragma unroll
      for (int i8 = 0; i8 < 8; ++i8) {
        short tmp[8];
#pragma unroll
        for (int j = 0; j < 8; ++j) {
          int i = i8 * 8 + j;
          float v = rv ? xp[i * (HH * WW)] : 0.0f;
          tmp[j] = f2bf(v * gam_s[i0 + i]);
        }
        char* dst = (char*)xs_base + ((i8 * 16) ^ xs_sw);
        *reinterpret_cast<bf16x8*>(dst) = *reinterpret_cast<const bf16x8*>(tmp);
      }
    }
    for (int tap = 0; tap < TAPS; ++tap) {
      __syncthreads();
#pragma unroll
      for (int j = 0; j < 4; ++j) {
        int s = t + 256 * j;
        int row = s >> 3, sl = s & 7;
        int kbyte = (sl * 16) ^ ((row & 7) << 4);
        const short* src = Wr + ((size_t)(ot * 128 + row) * TAPS + tap) * CIN +
                           i0 + (kbyte >> 1);
        *reinterpret_cast<bf16x8*>((char*)As + row * 128 + sl * 16) =
            *reinterpret_cast<const bf16x8*>(src);
      }
      __syncthreads();

      const int dy = tap / 3 - 1, dx = tap % 3 - 1;
      bf16x8 afr[2][4], bfr[2][4];
#pragma unroll
      for (int kk = 0; kk < 2; ++kk) {
        const int kb = kk * 64 + (lane >> 4) * 16;
#pragma unroll
        for (int m = 0; m < 4; ++m) {
          int row = wr * 64 + m * 16 + (lane & 15);
          afr[kk][m] = *reinterpret_cast<const bf16x8*>(
              (const char*)As + row * 128 + (kb ^ ((row & 7) << 4)));
        }
#pragma unroll
        for (int n = 0; n < 4; ++n) {
          int p = wc * 64 + n * 16 + (lane & 15);
          int r = p >> 6, c = p & 63;
          int cc = c + dx;
          bool val = (cc >= 0) && (cc < WW);
          int ccl = val ? cc : 0;
          int rr = r + dy + 1;
          bf16x8 f = *reinterpret_cast<const bf16x8*>(
              (const char*)Xs + (rr * 64 + ccl) * 128 + (kb ^ ((ccl & 7) << 4)));
          if (!val) f = (bf16x8){0, 0, 0, 0, 0, 0, 0, 0};
          bfr[kk][n] = f;
        }
      }
#pragma unroll
      for (int m = 0; m < 4; ++m)
#pragma unroll
        for (int n = 0; n < 4; ++n)
#pragma unroll
          for (int kk = 0; kk < 2; ++kk)
            acc[m][n] = __builtin_amdgcn_mfma_f32_16x16x32_bf16(
                afr[kk][m], bfr[kk][n], acc[m][n], 0, 0, 0);
    }
  }

#pragma unroll
  for (int m = 0; m < 4; ++m) {
#pragma unroll
    for (int n = 0; n < 4; ++n) {
#pragma unroll
      for (int j = 0; j < 4; ++j) {
        int o_l = wr * 64 + m * 16 + (lane >> 4) * 4 + j;
        int o = ot * 128 + o_l;
        int p = wc * 64 + n * 16 + (lane & 15);
        int yy = sp * 2 + (p >> 6);
        int cx = p & 63;
        out[(((size_t)b * COUT + o) * HH + yy) * WW + cx] = d_s[o_l] * acc[m][n][j];
      }
    }
  }
}

extern "C" void kernel_launch(void* const* d_in, const int* in_sizes, int n_in,
                              void* d_out, int out_size, void* d_ws, size_t ws_size,
                              hipStream_t stream) {
  const float* x = (const float*)d_in[0];
  const float* y = (const float*)d_in[1];
  const float* w_conv = (const float*)d_in[2];
  const float* w_gamma = (const float*)d_in[3];
  const float* b_gamma = (const float*)d_in[4];
  float* out = (float*)d_out;

  char* ws = (char*)d_ws;
  short* Wr = (short*)ws;                        // 4,718,592 B
  float* gamma = (float*)(ws + 4718592);         // 32,768 B
  float* dsc = (float*)(ws + 4751360);           // 32,768 B
  float* s2 = (float*)(ws + 4784128);            // 1,048,576 B
  char* zbuf = ws + 5832704;                     // 4,096 B (zero page)
  short* xm = (short*)(ws + 5836800);            // 67,108,864 B
  const size_t NEED = 5836800 + (size_t)NB * HH * WW * CIN * 2;

  const bool fast = ws_size >= NEED;

  hipLaunchKernelGGL(k_gamma, dim3(NB), dim3(512), 0, stream, y, w_gamma, b_gamma,
                     gamma, fast ? (float*)zbuf : (float*)nullptr);
  hipLaunchKernelGGL(k_prep, dim3(COUT), dim3(256), 0, stream, w_conv, s2, Wr);
  hipLaunchKernelGGL(k_d, dim3(NB), dim3(512), 0, stream, gamma, s2, dsc);
  if (fast) {
    hipLaunchKernelGGL(k_xmod, dim3(HH, NB), dim3(256), 0, stream, x, gamma, xm);
    hipLaunchKernelGGL(k_conv2, dim3(2048), dim3(256), 0, stream, xm, Wr,
                       (const short*)zbuf, dsc, out);
  } else {
    hipLaunchKernelGGL(k_conv_fb, dim3(32, 4, NB), dim3(256), 0, stream, x, Wr,
                       gamma, dsc, out);
  }
}